// Round 6
// baseline (1514.414 us; speedup 1.0000x reference)
//
#include <hip/hip_runtime.h>
#include <math.h>

#define S_LEN 512
#define CH 8    // timestep chunk held in SGPRs (24 floats), double-buffered

typedef float v2f __attribute__((ext_vector_type(2)));

__device__ __forceinline__ float fast_rcp(float x) { return __builtin_amdgcn_rcpf(x); }
__device__ __forceinline__ float fast_rsq(float x) { return __builtin_amdgcn_rsqf(x); }
__device__ __forceinline__ float exp2s(float x)    { return __builtin_amdgcn_exp2f(x); }
__device__ __forceinline__ v2f exp2v(v2f a) { return (v2f){exp2s(a.x), exp2s(a.y)}; }
__device__ __forceinline__ v2f rcpv(v2f a)  { return (v2f){fast_rcp(a.x), fast_rcp(a.y)}; }
__device__ __forceinline__ v2f rsqv(v2f a)  { return (v2f){fast_rsq(a.x), fast_rsq(a.y)}; }
__device__ __forceinline__ v2f maxv(v2f a, v2f b) { return __builtin_elementwise_max(a, b); }

// quad_perm DPP add: v += lanes-permuted(v) within each group of 4. Pure VALU.
template <int CTRL>
__device__ __forceinline__ float dpp_add(float v) {
    int t = __builtin_amdgcn_update_dpp(0, __builtin_bit_cast(int, v), CTRL, 0xF, 0xF, true);
    return v + __builtin_bit_cast(float, t);
}

// 2 waves/block, each wave owns one batch element; thread packs points
// (lane, lane+64) in v2f. 2048 blocks; LDS 6.6KB; target 24 waves/CU.
__global__ __launch_bounds__(128, 6) void prnn_kernel(
    const float* __restrict__ x,
    const float* __restrict__ W1,
    const float* __restrict__ W2,
    float* __restrict__ out)
{
    const float MU      = (float)(3130.0 / 2.6);
    const float THREE_MU= (float)(3.0 * (3130.0 / 2.6));
    const float C43     = (float)(4.0 * (3130.0 / 2.6) / 3.0);
    const float C23     = (float)(2.0 * (3130.0 / 2.6) / 3.0);
    const float CP      = (float)(7825.0 / 3.0);
    const float Cf      = 0.003407f;
    const float K2      = (float)(1.4426950408889634 / 0.003407);  // log2(e)/C
    const float R3M     = (float)(1.0 / (3.0 * (3130.0 / 2.6)));
    const float AR3M    = (float)(64.8 / (3.0 * (3130.0 / 2.6)));
    const float L2B3MC  = 1.449290f;                               // log2(B/(3muC))
    const float LOG2E   = 1.4426950408889634f;
    const float LNI08   = (float)(0.8 * 0.6931471805599453);

    const int lane = threadIdx.x & 63;
    const int wv   = threadIdx.x >> 6;
    const int b    = blockIdx.x * 2 + wv;

    // Fold fc1 + elasticity into per-point deviatoric/pressure maps (R5 scheme)
    v2f D0[3], D1[3], D3[3], pv[3];
    #pragma unroll
    for (int f = 0; f < 3; ++f) {
        const int mA = lane, mB = lane + 64;
        v2f av = (v2f){ W1[(mA*3 + 0)*3 + f], W1[(mB*3 + 0)*3 + f] };
        v2f bv = (v2f){ W1[(mA*3 + 1)*3 + f], W1[(mB*3 + 1)*3 + f] };
        v2f cv = (v2f){ W1[(mA*3 + 2)*3 + f], W1[(mB*3 + 2)*3 + f] };
        D0[f] = C43*av - C23*bv;
        D1[f] = C43*bv - C23*av;
        D3[f] = MU*cv;
        pv[f] = CP*(av + bv);
    }
    v2f w2[3][3];
    #pragma unroll
    for (int o = 0; o < 3; ++o)
        #pragma unroll
        for (int j = 0; j < 3; ++j)
            w2[o][j] = (v2f){ W2[o*384 + lane*3 + j], W2[o*384 + (lane+64)*3 + j] };

    __shared__ float part[2][CH][3][17];    // 6.6 KB

    const float* xb   = x   + (size_t)b * (S_LEN*3);
    float*       outb = out + (size_t)b * (S_LEN*3);

    // x chunks in SGPRs (uniform loads), double-buffered
    float cur[CH*3], nxt[CH*3];
    #pragma unroll
    for (int j = 0; j < CH*3; ++j) cur[j] = xb[j];

    v2f sp0 = (v2f){0.f,0.f}, sp1 = sp0, sp3 = sp0, kap = sp0;

    #pragma unroll 1
    for (int tc = 0; tc < S_LEN; tc += CH) {
        // prefetch next chunk (wraps to 0 on the last iter — harmless reload)
        const float* xn = xb + ((tc + CH < S_LEN) ? (tc + CH) : 0) * 3;
        #pragma unroll
        for (int j = 0; j < CH*3; ++j) nxt[j] = xn[j];

        #pragma unroll
        for (int tt = 0; tt < CH; ++tt) {
            const float x0 = cur[tt*3+0], x1 = cur[tt*3+1], x2 = cur[tt*3+2];

            // trial deviatoric stress + pressure
            v2f d0 = D0[0]*x0 + D0[1]*x1 + D0[2]*x2 - sp0;
            v2f d1 = D1[0]*x0 + D1[1]*x1 + D1[2]*x2 - sp1;
            v2f d3 = D3[0]*x0 + D3[1]*x1 + D3[2]*x2 - sp3;
            v2f p  = pv[0]*x0 + pv[1]*x1 + pv[2]*x2;

            // q^2 = 3(d0^2 + d1^2 + d0 d1 + d3^2)
            v2f h   = d0*d0 + d1*d1 + d0*d1 + d3*d3;
            v2f dot = maxv(3.0f*h, (v2f){1e-24f,1e-24f});
            v2f qi  = rsqv(dot);
            v2f q   = dot * qi;

            // dg = max(0, u0 + C*W(z)) — exact root of the return map
            v2f u0  = q*R3M - AR3M;
            v2f l2z = L2B3MC - (kap + u0)*K2;
            v2f z   = exp2v(l2z);
            v2f w   = maxv(LNI08*l2z, z*rcpv(1.0f + z));
            v2f y   = exp2v(w * LOG2E);
            v2f F   = w*y - z;
            v2f Fp  = w*y + y;
            v2f den = Fp*Fp + (F*y)*(-1.0f - 0.5f*w);
            w = w - (F*Fp)*rcpv(den);
            v2f dg  = maxv(u0 + Cf*w, (v2f){0.f,0.f});

            // radial return in stress space
            v2f t2 = THREE_MU*dg*qi;
            v2f u  = 1.0f - t2;
            sp0 += t2*d0; sp1 += t2*d1; sp3 += t2*d3;
            kap += dg;
            v2f r0 = u*d0 + p;
            v2f r1 = u*d1 + p;
            v2f r3 = u*d3;

            // fc2 contribution, pair-sum
            v2f a0 = w2[0][0]*r0 + w2[0][1]*r1 + w2[0][2]*r3;
            v2f a1 = w2[1][0]*r0 + w2[1][1]*r1 + w2[1][2]*r3;
            v2f a2 = w2[2][0]*r0 + w2[2][1]*r1 + w2[2][2]*r3;
            float c0 = a0.x + a0.y;
            float c1 = a1.x + a1.y;
            float c2 = a2.x + a2.y;

            // 4-lane reduce via DPP (quad_perm xor1 = 0xB1, xor2 = 0x4E)
            c0 = dpp_add<0xB1>(c0); c0 = dpp_add<0x4E>(c0);
            c1 = dpp_add<0xB1>(c1); c1 = dpp_add<0x4E>(c1);
            c2 = dpp_add<0xB1>(c2); c2 = dpp_add<0x4E>(c2);
            if ((lane & 3) == 0) {
                const int g = lane >> 2;
                part[wv][tt][0][g] = c0;
                part[wv][tt][1][g] = c1;
                part[wv][tt][2][g] = c2;
            }
        }
        // finish: lane r<24 handles (tt=r/3, o=r%3). Same-wave DS ordering is
        // program-order — no barrier needed (waves are independent).
        if (lane < 24) {
            const int rtt = lane / 3, ro = lane - rtt*3;
            float s = 0.0f;
            #pragma unroll
            for (int g = 0; g < 16; ++g) s += part[wv][rtt][ro][g];
            outb[tc*3 + lane] = s;
        }
        #pragma unroll
        for (int j = 0; j < CH*3; ++j) cur[j] = nxt[j];
    }
}

extern "C" void kernel_launch(void* const* d_in, const int* in_sizes, int n_in,
                              void* d_out, int out_size, void* d_ws, size_t ws_size,
                              hipStream_t stream) {
    const float* x  = (const float*)d_in[0];
    const float* W1 = (const float*)d_in[1];
    const float* W2 = (const float*)d_in[2];
    float* out = (float*)d_out;
    prnn_kernel<<<2048, 128, 0, stream>>>(x, W1, W2, out);
}

// Round 7
// 536.687 us; speedup vs baseline: 2.8218x; 2.8218x over previous
//
#include <hip/hip_runtime.h>
#include <math.h>

#define S_LEN 512
#define CH 8

__device__ __forceinline__ float fast_rcp(float x) { return __builtin_amdgcn_rcpf(x); }
__device__ __forceinline__ float fast_rsq(float x) { return __builtin_amdgcn_rsqf(x); }
__device__ __forceinline__ float exp2s(float x)    { return __builtin_amdgcn_exp2f(x); }

// quad_perm DPP add: v += permuted(v) within each group of 4 lanes. Pure VALU.
template <int CTRL>
__device__ __forceinline__ float dpp_add(float v) {
    int t = __builtin_amdgcn_update_dpp(0, __builtin_bit_cast(int, v), CTRL, 0xF, 0xF, true);
    return v + __builtin_bit_cast(float, t);
}

// One block per batch element; 128 threads = 128 material points (1/lane,
// 2 waves). 4096 blocks -> 8192 waves -> 32 waves/CU (8/SIMD) to hide the
// per-step rsq/exp2/rcp dependency chain. LDS 9.4 KB -> thread-capped
// occupancy, not LDS-capped. NO private arrays (R6 scratch lesson).
__global__ __launch_bounds__(128, 6) void prnn_kernel(
    const float* __restrict__ x,
    const float* __restrict__ W1,
    const float* __restrict__ W2,
    float* __restrict__ out)
{
    const float MU      = (float)(3130.0 / 2.6);
    const float THREE_MU= (float)(3.0 * (3130.0 / 2.6));
    const float C43     = (float)(4.0 * (3130.0 / 2.6) / 3.0);
    const float C23     = (float)(2.0 * (3130.0 / 2.6) / 3.0);
    const float CP      = (float)(7825.0 / 3.0);
    const float Cf      = 0.003407f;
    const float K2      = (float)(1.4426950408889634 / 0.003407);  // log2(e)/C
    const float R3M     = (float)(1.0 / (3.0 * (3130.0 / 2.6)));
    const float AR3M    = (float)(64.8 / (3.0 * (3130.0 / 2.6)));
    const float L2B3MC  = 1.449290f;                               // log2(B/(3muC))
    const float LOG2E   = 1.4426950408889634f;
    const float LNI08   = (float)(0.8 * 0.6931471805599453);

    const int tid  = threadIdx.x;      // == material point index m in [0,128)
    const int lane = tid & 63;
    const int wv   = tid >> 6;
    const int b    = blockIdx.x;

    // Fold fc1 + elasticity into per-point deviatoric/pressure maps
    float D0[3], D1[3], D3[3], pvr[3];
    #pragma unroll
    for (int f = 0; f < 3; ++f) {
        const float av = W1[(tid*3 + 0)*3 + f];
        const float bv = W1[(tid*3 + 1)*3 + f];
        const float cv = W1[(tid*3 + 2)*3 + f];
        D0[f]  = C43*av - C23*bv;
        D1[f]  = C43*bv - C23*av;
        D3[f]  = MU*cv;
        pvr[f] = CP*(av + bv);
    }
    float w2r[3][3];
    #pragma unroll
    for (int o = 0; o < 3; ++o)
        #pragma unroll
        for (int j = 0; j < 3; ++j)
            w2r[o][j] = W2[o*384 + tid*3 + j];

    __shared__ float xs[S_LEN*3];            // 6 KB, shared by both waves
    __shared__ float part[2][CH][3][17];     // 3.3 KB

    const float* xb = x + (size_t)b * (S_LEN*3);
    for (int i = tid; i < S_LEN*3; i += 128) xs[i] = xb[i];
    __syncthreads();

    // State: deviatoric plastic stress sp = 2mu*dev(ep) (3 live comps), kappa
    float sp0 = 0.f, sp1 = 0.f, sp3 = 0.f, kap = 0.f;
    float* outb = out + (size_t)b * (S_LEN*3);

    #pragma unroll 1
    for (int tc = 0; tc < S_LEN; tc += CH) {
        #pragma unroll
        for (int tt = 0; tt < CH; ++tt) {
            const int t = tc + tt;
            const float x0 = xs[t*3+0], x1 = xs[t*3+1], x2 = xs[t*3+2];

            // trial deviatoric stress + pressure (precomputed maps)
            const float d0 = D0[0]*x0 + D0[1]*x1 + D0[2]*x2 - sp0;
            const float d1 = D1[0]*x0 + D1[1]*x1 + D1[2]*x2 - sp1;
            const float d3 = D3[0]*x0 + D3[1]*x1 + D3[2]*x2 - sp3;
            const float p  = pvr[0]*x0 + pvr[1]*x1 + pvr[2]*x2;

            // q^2 = 3(d0^2 + d1^2 + d0 d1 + d3^2)   [d2 = -(d0+d1)]
            const float h   = d0*d0 + d1*d1 + d0*d1 + d3*d3;
            const float dot = fmaxf(3.0f*h, 1e-24f);
            const float qi  = fast_rsq(dot);
            const float q   = dot * qi;

            // dg = max(0, u0 + C*W(z)) — exact root of the return map.
            // Overflow (z=inf) propagates NaN -> fmaxf picks 0 -> correct elastic.
            const float u0  = q*R3M - AR3M;
            const float l2z = L2B3MC - (kap + u0)*K2;
            const float z   = exp2s(l2z);
            float w = fmaxf(LNI08*l2z, z*fast_rcp(1.0f + z));   // init
            // one Halley step on F = w e^w - z (cubic)
            const float y   = exp2s(w * LOG2E);
            const float F   = w*y - z;
            const float Fp  = w*y + y;
            const float den = Fp*Fp + (F*y)*(-1.0f - 0.5f*w);
            w = w - (F*Fp)*fast_rcp(den);
            const float dg  = fmaxf(u0 + Cf*w, 0.0f);

            // radial return in stress space (exact no-op where dg==0)
            const float t2 = THREE_MU*dg*qi;
            const float u  = 1.0f - t2;
            sp0 += t2*d0; sp1 += t2*d1; sp3 += t2*d3;
            kap += dg;
            const float r0 = u*d0 + p;
            const float r1 = u*d1 + p;
            const float r3 = u*d3;

            // fc2 contribution
            float c0 = w2r[0][0]*r0 + w2r[0][1]*r1 + w2r[0][2]*r3;
            float c1 = w2r[1][0]*r0 + w2r[1][1]*r1 + w2r[1][2]*r3;
            float c2 = w2r[2][0]*r0 + w2r[2][1]*r1 + w2r[2][2]*r3;

            // 4-lane reduce via DPP quad_perm (xor1=0xB1, xor2=0x4E)
            c0 = dpp_add<0xB1>(c0); c0 = dpp_add<0x4E>(c0);
            c1 = dpp_add<0xB1>(c1); c1 = dpp_add<0x4E>(c1);
            c2 = dpp_add<0xB1>(c2); c2 = dpp_add<0x4E>(c2);
            if ((lane & 3) == 0) {
                const int g = lane >> 2;     // 0..15
                part[wv][tt][0][g] = c0;
                part[wv][tt][1][g] = c1;
                part[wv][tt][2][g] = c2;
            }
        }
        __syncthreads();
        // finish: thread r<24 handles (tt=r/3, o=r%3); sums both waves' 16 slots
        if (tid < 24) {
            const int rtt = tid / 3, ro = tid - rtt*3;
            float s = 0.0f;
            #pragma unroll
            for (int g = 0; g < 16; ++g)
                s += part[0][rtt][ro][g] + part[1][rtt][ro][g];
            outb[tc*3 + tid] = s;
        }
        __syncthreads();
    }
}

extern "C" void kernel_launch(void* const* d_in, const int* in_sizes, int n_in,
                              void* d_out, int out_size, void* d_ws, size_t ws_size,
                              hipStream_t stream) {
    const float* x  = (const float*)d_in[0];
    const float* W1 = (const float*)d_in[1];
    const float* W2 = (const float*)d_in[2];
    float* out = (float*)d_out;
    prnn_kernel<<<4096, 128, 0, stream>>>(x, W1, W2, out);
}

// Round 8
// 384.142 us; speedup vs baseline: 3.9423x; 1.3971x over previous
//
#include <hip/hip_runtime.h>
#include <math.h>

#define S_LEN 512
#define CH 8

typedef float v2f __attribute__((ext_vector_type(2)));

__device__ __forceinline__ float fast_rcp(float x) { return __builtin_amdgcn_rcpf(x); }
__device__ __forceinline__ float fast_rsq(float x) { return __builtin_amdgcn_rsqf(x); }
__device__ __forceinline__ float exp2s(float x)    { return __builtin_amdgcn_exp2f(x); }
__device__ __forceinline__ v2f exp2v(v2f a) { return (v2f){exp2s(a.x), exp2s(a.y)}; }
__device__ __forceinline__ v2f rcpv(v2f a)  { return (v2f){fast_rcp(a.x), fast_rcp(a.y)}; }
__device__ __forceinline__ v2f rsqv(v2f a)  { return (v2f){fast_rsq(a.x), fast_rsq(a.y)}; }
__device__ __forceinline__ v2f maxv(v2f a, v2f b) { return __builtin_elementwise_max(a, b); }

// quad_perm DPP add (pure VALU; old = src so backend can fuse v_add_f32_dpp)
template <int CTRL>
__device__ __forceinline__ float dpp_add(float v) {
    int vi = __builtin_bit_cast(int, v);
    int t  = __builtin_amdgcn_update_dpp(vi, vi, CTRL, 0xF, 0xF, true);
    return v + __builtin_bit_cast(float, t);
}

// 2 independent waves/block; each wave owns one batch element; each thread
// packs points (lane, lane+64) in v2f (pk code density: per-wave overhead
// amortized over 128 points). Full 8-step unroll to hide the trans chain.
// NO barriers: all LDS regions are per-wave, DS ops are program-ordered
// within a wave. 2048 blocks -> 8 blocks/CU (LDS 19.4 KB), 16 waves/CU.
__global__ __launch_bounds__(128, 4) void prnn_kernel(
    const float* __restrict__ x,
    const float* __restrict__ W1,
    const float* __restrict__ W2,
    float* __restrict__ out)
{
    const float MU      = (float)(3130.0 / 2.6);
    const float THREE_MU= (float)(3.0 * (3130.0 / 2.6));
    const float C43     = (float)(4.0 * (3130.0 / 2.6) / 3.0);
    const float C23     = (float)(2.0 * (3130.0 / 2.6) / 3.0);
    const float CP      = (float)(7825.0 / 3.0);
    const float Cf      = 0.003407f;
    const float K2      = (float)(1.4426950408889634 / 0.003407);  // log2(e)/C
    const float R3M     = (float)(1.0 / (3.0 * (3130.0 / 2.6)));
    const float AR3M    = (float)(64.8 / (3.0 * (3130.0 / 2.6)));
    const float L2B3MC  = 1.449290f;                               // log2(B/(3muC))
    const float LOG2E   = 1.4426950408889634f;
    const float LNI08   = (float)(0.8 * 0.6931471805599453);

    const int lane = threadIdx.x & 63;
    const int wv   = threadIdx.x >> 6;
    const int b    = blockIdx.x * 2 + wv;

    // Fold fc1 + elasticity into per-point deviatoric/pressure maps
    v2f D0[3], D1[3], D3[3], pv[3];
    #pragma unroll
    for (int f = 0; f < 3; ++f) {
        const int mA = lane, mB = lane + 64;
        v2f av = (v2f){ W1[(mA*3 + 0)*3 + f], W1[(mB*3 + 0)*3 + f] };
        v2f bv = (v2f){ W1[(mA*3 + 1)*3 + f], W1[(mB*3 + 1)*3 + f] };
        v2f cv = (v2f){ W1[(mA*3 + 2)*3 + f], W1[(mB*3 + 2)*3 + f] };
        D0[f] = C43*av - C23*bv;
        D1[f] = C43*bv - C23*av;
        D3[f] = MU*cv;
        pv[f] = CP*(av + bv);
    }
    v2f w2[3][3];
    #pragma unroll
    for (int o = 0; o < 3; ++o)
        #pragma unroll
        for (int j = 0; j < 3; ++j)
            w2[o][j] = (v2f){ W2[o*384 + lane*3 + j], W2[o*384 + (lane+64)*3 + j] };

    __shared__ float xs[2][S_LEN*4];         // padded stride-4, 16 KB
    __shared__ float part[2][CH][3][17];     // 3.3 KB

    // Per-wave staging of this wave's batch element (no cross-wave sharing)
    const float* xb = x + (size_t)b * (S_LEN*3);
    for (int i = lane; i < S_LEN*3; i += 64) {
        const int t = i / 3, c = i - 3*t;
        xs[wv][t*4 + c] = xb[i];
    }
    // no __syncthreads: same wave wrote, same wave reads (DS program order)

    v2f sp0 = (v2f){0.f,0.f}, sp1 = sp0, sp3 = sp0, kap = sp0;
    float* outb = out + (size_t)b * (S_LEN*3);

    #pragma unroll 1
    for (int tc = 0; tc < S_LEN; tc += CH) {
        #pragma unroll
        for (int tt = 0; tt < CH; ++tt) {
            const int t = tc + tt;
            const float x0 = xs[wv][t*4+0];
            const float x1 = xs[wv][t*4+1];
            const float x2 = xs[wv][t*4+2];

            // trial deviatoric stress + pressure
            v2f d0 = D0[0]*x0 + D0[1]*x1 + D0[2]*x2 - sp0;
            v2f d1 = D1[0]*x0 + D1[1]*x1 + D1[2]*x2 - sp1;
            v2f d3 = D3[0]*x0 + D3[1]*x1 + D3[2]*x2 - sp3;
            v2f p  = pv[0]*x0 + pv[1]*x1 + pv[2]*x2;

            // q^2 = 3(d0^2 + d1^2 + d0 d1 + d3^2)
            v2f h   = d0*d0 + d1*d1 + d0*d1 + d3*d3;
            v2f dot = maxv(3.0f*h, (v2f){1e-24f,1e-24f});
            v2f qi  = rsqv(dot);
            v2f q   = dot * qi;

            // dg = max(0, u0 + C*W(z)) — exact root of the return map
            v2f u0  = q*R3M - AR3M;
            v2f l2z = L2B3MC - (kap + u0)*K2;
            v2f z   = exp2v(l2z);
            v2f w   = maxv(LNI08*l2z, z*rcpv(1.0f + z));
            v2f y   = exp2v(w * LOG2E);
            v2f F   = w*y - z;
            v2f Fp  = w*y + y;
            v2f den = Fp*Fp + (F*y)*(-1.0f - 0.5f*w);
            w = w - (F*Fp)*rcpv(den);
            v2f dg  = maxv(u0 + Cf*w, (v2f){0.f,0.f});

            // radial return in stress space (exact no-op where dg==0)
            v2f t2 = THREE_MU*dg*qi;
            v2f u  = 1.0f - t2;
            sp0 += t2*d0; sp1 += t2*d1; sp3 += t2*d3;
            kap += dg;
            v2f r0 = u*d0 + p;
            v2f r1 = u*d1 + p;
            v2f r3 = u*d3;

            // fc2 contribution, pair-sum
            v2f a0 = w2[0][0]*r0 + w2[0][1]*r1 + w2[0][2]*r3;
            v2f a1 = w2[1][0]*r0 + w2[1][1]*r1 + w2[1][2]*r3;
            v2f a2 = w2[2][0]*r0 + w2[2][1]*r1 + w2[2][2]*r3;
            float c0 = a0.x + a0.y;
            float c1 = a1.x + a1.y;
            float c2 = a2.x + a2.y;

            // 4-lane reduce via DPP quad_perm (xor1=0xB1, xor2=0x4E)
            c0 = dpp_add<0xB1>(c0); c0 = dpp_add<0x4E>(c0);
            c1 = dpp_add<0xB1>(c1); c1 = dpp_add<0x4E>(c1);
            c2 = dpp_add<0xB1>(c2); c2 = dpp_add<0x4E>(c2);
            if ((lane & 3) == 0) {
                const int g = lane >> 2;     // 0..15
                part[wv][tt][0][g] = c0;
                part[wv][tt][1][g] = c1;
                part[wv][tt][2][g] = c2;
            }
        }
        // finish (same wave): lane r<24 handles (tt=r/3, o=r%3)
        if (lane < 24) {
            const int rtt = lane / 3, ro = lane - rtt*3;
            float s = 0.0f;
            #pragma unroll
            for (int g = 0; g < 16; ++g) s += part[wv][rtt][ro][g];
            outb[tc*3 + lane] = s;
        }
    }
}

extern "C" void kernel_launch(void* const* d_in, const int* in_sizes, int n_in,
                              void* d_out, int out_size, void* d_ws, size_t ws_size,
                              hipStream_t stream) {
    const float* x  = (const float*)d_in[0];
    const float* W1 = (const float*)d_in[1];
    const float* W2 = (const float*)d_in[2];
    float* out = (float*)d_out;
    prnn_kernel<<<2048, 128, 0, stream>>>(x, W1, W2, out);
}